// Round 2
// baseline (170.820 us; speedup 1.0000x reference)
//
#include <hip/hip_runtime.h>
#include <math.h>

// MAM dense: C[m,n] = max_k(A[m,k]*W[n,k]) + min_k(A[m,k]*W[n,k]) + bias[n]
// A: [M,K] fp32, W: [N,K] fp32 (torch layout), C: [M,N]
//
// R15 = R14 resubmitted (R14 bench was an infra failure: "container failed
// twice" -- kernel never ran; source re-audited for bounds/ISA validity).
//
// R14 theory: R13 counters showed VALU-issue-bound (VALUBusy pegged,
// MfmaUtil 0, HBM 5%): 4 VALU instr per element per k-pair
// (2 mul + max3 + min3) = 54.6 us issue floor, measured 103 us.
// gfx950 has v_pk_mul_f32 (full-rate VOP3P packed fp32) but no packed
// f32 max/min -> collapse the 2 muls into 1 pk_mul: 3 instr per k-pair
// (-25% VALU). Requires k-pair-interleaved LDS strips [k/2][m][2] so one
// ds_read_b128 yields two even-aligned (k_even,k_odd) operand pairs.
// Staging writes become 2x ds_write_b64 per float4 (was 4x b32).
// Read pattern is 4-way bank-aliased (8 addrs @ 64B stride) vs old 2-way;
// LDS stays <~45% of VALU cycles so it should hide under issue.

#define TS 64
#define BK 16
#define RS 132               // interleaved row stride: 64 m-pairs * 2 + 4 pad
#define STRIPF (8 * RS)      // (BK/2) rows per strip = 1056 floats

typedef __attribute__((ext_vector_type(2))) float f32x2;
typedef __attribute__((ext_vector_type(4))) float f32x4;

__device__ __forceinline__ f32x2 lo2(f32x4 v) { return __builtin_shufflevector(v, v, 0, 1); }
__device__ __forceinline__ f32x2 hi2(f32x4 v) { return __builtin_shufflevector(v, v, 2, 3); }

__device__ __forceinline__ void mam_upd_pk(float& mx, float& mn, f32x2 a, f32x2 b) {
    f32x2 p;
    asm("v_pk_mul_f32 %0, %1, %2" : "=v"(p) : "v"(a), "v"(b));
    asm("v_max3_f32 %0, %1, %2, %0" : "+v"(mx) : "v"(p.x), "v"(p.y));
    asm("v_min3_f32 %0, %1, %2, %0" : "+v"(mn) : "v"(p.x), "v"(p.y));
}

__global__
__attribute__((amdgpu_flat_work_group_size(256, 256)))
__attribute__((amdgpu_waves_per_eu(2, 2)))
void mam_sk(
    const float* __restrict__ A, const float* __restrict__ W,
    const float* __restrict__ bias, float* __restrict__ C,
    int M, int N, int K)
{
    // union: [0..4*STRIPF) sA strips, [4*STRIPF..8*STRIPF) sW strips;
    // after the main loop (barrier) the same memory holds cmx/cmn (64x64 each;
    // 8192 floats <= 8*STRIPF = 8448).
    __shared__ __align__(16) float smem[8 * STRIPF];   // 33792 B
    float* cmx = smem;
    float* cmn = smem + TS * TS;

    const int t    = threadIdx.x;
    const int w    = t >> 6;        // wave id == k-group
    const int lane = t & 63;
    const int ty   = lane >> 3;     // m micro thread (8 rows)
    const int tx   = lane & 7;      // n micro thread (8 cols)
    const int m0   = blockIdx.y * TS;
    const int n0   = blockIdx.x * TS;
    const int kc   = K >> 2;        // 256 k per wave
    const int kb0  = w * kc;

    const int sr = lane >> 2;       // staging row 0..15
    const int sc = lane & 3;        // staging k-quad 0..3

    float* sAw = smem + (size_t)w * STRIPF;          // this wave's A strip
    float* sWw = smem + (size_t)(4 + w) * STRIPF;    // this wave's W strip

    const float* Ap = A + (size_t)(m0 + sr) * K + kb0 + sc * 4;
    const float* Wp = W + (size_t)(n0 + sr) * K + kb0 + sc * 4;

    float mx[8][8], mn[8][8];
#pragma unroll
    for (int i = 0; i < 8; ++i)
#pragma unroll
        for (int j = 0; j < 8; ++j) {
            mx[i][j] = -INFINITY;
            mn[i][j] =  INFINITY;
        }

    float4 ra[4], rw[4];
#pragma unroll
    for (int q = 0; q < 4; ++q) {
        ra[q] = *(const float4*)(Ap + (size_t)q * 16 * K);
        rw[q] = *(const float4*)(Wp + (size_t)q * 16 * K);
    }
    Ap += BK;
    Wp += BK;

    const int nStages = kc / BK;    // 16
    for (int s = 0; s < nStages; ++s) {
        // scatter current stage into this wave's strip, k-pair interleaved:
        // strip row kp holds (A[2kp][m], A[2kp+1][m]) at float offset m*2.
        // float4 (k0..k3) for row mI -> (x,y) to row sc*2, (z,w) to row sc*2+1.
        // (no barrier: strip is wave-private; same-wave DS ops are ordered)
#pragma unroll
        for (int q = 0; q < 4; ++q) {
            const int mI = sr + q * 16;
            *(float2*)&sAw[(sc * 2 + 0) * RS + mI * 2] = make_float2(ra[q].x, ra[q].y);
            *(float2*)&sAw[(sc * 2 + 1) * RS + mI * 2] = make_float2(ra[q].z, ra[q].w);
            *(float2*)&sWw[(sc * 2 + 0) * RS + mI * 2] = make_float2(rw[q].x, rw[q].y);
            *(float2*)&sWw[(sc * 2 + 1) * RS + mI * 2] = make_float2(rw[q].z, rw[q].w);
        }
        // prefetch next stage while computing this one
        if (s + 1 < nStages) {
#pragma unroll
            for (int q = 0; q < 4; ++q) {
                ra[q] = *(const float4*)(Ap + (size_t)q * 16 * K);
                rw[q] = *(const float4*)(Wp + (size_t)q * 16 * K);
            }
            Ap += BK;
            Wp += BK;
        }

#pragma unroll
        for (int kp = 0; kp < BK / 2; ++kp) {
            const float* rA = sAw + kp * RS + ty * 16;
            const float* rW = sWw + kp * RS + tx * 16;
            f32x4 A0 = *(const f32x4*)(rA + 0);
            f32x4 A1 = *(const f32x4*)(rA + 4);
            f32x4 A2 = *(const f32x4*)(rA + 8);
            f32x4 A3 = *(const f32x4*)(rA + 12);
            f32x4 W0 = *(const f32x4*)(rW + 0);
            f32x4 W1 = *(const f32x4*)(rW + 4);
            f32x4 W2 = *(const f32x4*)(rW + 8);
            f32x4 W3 = *(const f32x4*)(rW + 12);

            f32x2 av[8] = {lo2(A0), hi2(A0), lo2(A1), hi2(A1),
                           lo2(A2), hi2(A2), lo2(A3), hi2(A3)};
            f32x2 bv[8] = {lo2(W0), hi2(W0), lo2(W1), hi2(W1),
                           lo2(W2), hi2(W2), lo2(W3), hi2(W3)};

#pragma unroll
            for (int i = 0; i < 8; ++i)
#pragma unroll
                for (int j = 0; j < 8; ++j)
                    mam_upd_pk(mx[i][j], mn[i][j], av[i], bv[j]);
        }
    }

    // strips now dead; cmx/cmn overlap them -> drain all waves first
    __syncthreads();

    // ---- cross-wave combine: sequential merge rounds through LDS ----
    for (int rnd = 0; rnd < 4; ++rnd) {
        if (w == rnd) {
#pragma unroll
            for (int i = 0; i < 8; ++i)
#pragma unroll
                for (int j = 0; j < 8; ++j) {
                    const int idx = (ty * 8 + i) * TS + tx * 8 + j;
                    if (rnd == 0) {
                        cmx[idx] = mx[i][j];
                        cmn[idx] = mn[i][j];
                    } else {
                        cmx[idx] = fmaxf(cmx[idx], mx[i][j]);
                        cmn[idx] = fminf(cmn[idx], mn[i][j]);
                    }
                }
        }
        __syncthreads();
    }

    // ---- bias + store: wave w writes micro-rows i = {2w, 2w+1} ----
    float4 blo = *(const float4*)(bias + n0 + tx * 8);
    float4 bhi = *(const float4*)(bias + n0 + tx * 8 + 4);
#pragma unroll
    for (int i2 = 0; i2 < 2; ++i2) {
        const int i   = w * 2 + i2;
        const int row = ty * 8 + i;
        const int idx = row * TS + tx * 8;
        float4 o0, o1;
        o0.x = cmx[idx + 0] + cmn[idx + 0] + blo.x;
        o0.y = cmx[idx + 1] + cmn[idx + 1] + blo.y;
        o0.z = cmx[idx + 2] + cmn[idx + 2] + blo.z;
        o0.w = cmx[idx + 3] + cmn[idx + 3] + blo.w;
        o1.x = cmx[idx + 4] + cmn[idx + 4] + bhi.x;
        o1.y = cmx[idx + 5] + cmn[idx + 5] + bhi.y;
        o1.z = cmx[idx + 6] + cmn[idx + 6] + bhi.z;
        o1.w = cmx[idx + 7] + cmn[idx + 7] + bhi.w;
        float4* p = (float4*)(C + (size_t)(m0 + row) * N + n0 + tx * 8);
        p[0] = o0;
        p[1] = o1;
    }
}

// ---- fallback (proven R2 kernel) for shapes the fast path can't take ----
#define BM 64
#define BN 64
#define FBK 32
#define LDSW 68

__device__ __forceinline__ void mam_upd_fb(float& mx, float& mn, float p0, float p1) {
    float nmx, nmn;
    asm("v_max3_f32 %0, %1, %2, %3" : "=v"(nmx) : "v"(p0), "v"(p1), "v"(mx));
    asm("v_min3_f32 %0, %1, %2, %3" : "=v"(nmn) : "v"(p0), "v"(p1), "v"(mn));
    mx = nmx;
    mn = nmn;
}

__global__ __launch_bounds__(256) void mam_fallback(
    const float* __restrict__ A, const float* __restrict__ W,
    const float* __restrict__ bias, float* __restrict__ C,
    int M, int N, int K)
{
    __shared__ float Asf[FBK][LDSW];
    __shared__ float Wsf[FBK][LDSW];

    const int t  = threadIdx.x;
    const int tx = t & 15;
    const int ty = t >> 4;
    const int m0 = blockIdx.y * BM;
    const int n0 = blockIdx.x * BN;
    const int r  = t >> 3;
    const int kq = t & 7;

    const float* Aptr = A + (size_t)(m0 + r) * K + kq * 4;
    const float* Wptr = W + (size_t)(n0 + r) * K + kq * 4;

    float vmax[4][4], vmin[4][4];
#pragma unroll
    for (int i = 0; i < 4; ++i)
#pragma unroll
        for (int j = 0; j < 4; ++j) {
            vmax[i][j] = -INFINITY;
            vmin[i][j] =  INFINITY;
        }

    for (int k0 = 0; k0 < K; k0 += FBK) {
        float4 a0 = *(const float4*)(Aptr);
        float4 a1 = *(const float4*)(Aptr + (size_t)32 * K);
        float4 w0 = *(const float4*)(Wptr);
        float4 w1 = *(const float4*)(Wptr + (size_t)32 * K);
        Aptr += FBK;
        Wptr += FBK;

        const int kk = kq * 4;
        Asf[kk + 0][r]      = a0.x;
        Asf[kk + 1][r]      = a0.y;
        Asf[kk + 2][r]      = a0.z;
        Asf[kk + 3][r]      = a0.w;
        Asf[kk + 0][r + 32] = a1.x;
        Asf[kk + 1][r + 32] = a1.y;
        Asf[kk + 2][r + 32] = a1.z;
        Asf[kk + 3][r + 32] = a1.w;

        Wsf[kk + 0][r]      = w0.x;
        Wsf[kk + 1][r]      = w0.y;
        Wsf[kk + 2][r]      = w0.z;
        Wsf[kk + 3][r]      = w0.w;
        Wsf[kk + 0][r + 32] = w1.x;
        Wsf[kk + 1][r + 32] = w1.y;
        Wsf[kk + 2][r + 32] = w1.z;
        Wsf[kk + 3][r + 32] = w1.w;

        __syncthreads();

#pragma unroll
        for (int k = 0; k < FBK; k += 2) {
            float4 ta0 = *(const float4*)&Asf[k    ][ty * 4];
            float4 ta1 = *(const float4*)&Asf[k + 1][ty * 4];
            float4 tb0 = *(const float4*)&Wsf[k    ][tx * 4];
            float4 tb1 = *(const float4*)&Wsf[k + 1][tx * 4];

            float a0v[4] = {ta0.x, ta0.y, ta0.z, ta0.w};
            float a1v[4] = {ta1.x, ta1.y, ta1.z, ta1.w};
            float b0v[4] = {tb0.x, tb0.y, tb0.z, tb0.w};
            float b1v[4] = {tb1.x, tb1.y, tb1.z, tb1.w};

#pragma unroll
            for (int i = 0; i < 4; ++i)
#pragma unroll
                for (int j = 0; j < 4; ++j) {
                    float p0 = a0v[i] * b0v[j];
                    float p1 = a1v[i] * b1v[j];
                    mam_upd_fb(vmax[i][j], vmin[i][j], p0, p1);
                }
        }
        __syncthreads();
    }

    float4 bv = *(const float4*)(bias + n0 + tx * 4);
#pragma unroll
    for (int i = 0; i < 4; ++i) {
        float4 o;
        o.x = vmax[i][0] + vmin[i][0] + bv.x;
        o.y = vmax[i][1] + vmin[i][1] + bv.y;
        o.z = vmax[i][2] + vmin[i][2] + bv.z;
        o.w = vmax[i][3] + vmin[i][3] + bv.w;
        *(float4*)(C + (size_t)(m0 + ty * 4 + i) * N + n0 + tx * 4) = o;
    }
}

extern "C" void kernel_launch(void* const* d_in, const int* in_sizes, int n_in,
                              void* d_out, int out_size, void* d_ws, size_t ws_size,
                              hipStream_t stream) {
    const float* x    = (const float*)d_in[0];
    const float* w    = (const float*)d_in[1];
    const float* bias = (const float*)d_in[2];
    float* out = (float*)d_out;

    const int N = in_sizes[2];
    const int K = in_sizes[1] / N;
    const int M = in_sizes[0] / K;

    const bool fast_ok = (K % (4 * BK) == 0) && (M % TS == 0) && (N % TS == 0);

    if (fast_ok) {
        dim3 grid(N / TS, M / TS);   // (16, 32) = 512 blocks
        mam_sk<<<grid, 256, 0, stream>>>(x, w, bias, out, M, N, K);
    } else {
        dim3 grid(N / BN, M / BM);
        mam_fallback<<<grid, 256, 0, stream>>>(x, w, bias, out, M, N, K);
    }
}

// Round 3
// 170.680 us; speedup vs baseline: 1.0008x; 1.0008x over previous
//
#include <hip/hip_runtime.h>
#include <math.h>

// MAM dense: C[m,n] = max_k(A[m,k]*W[n,k]) + min_k(A[m,k]*W[n,k]) + bias[n]
// A: [M,K] fp32, W: [N,K] fp32 (torch layout), C: [M,N]
//
// R16 = R15 + conflict-free bumped LDS layout.
// R15 post-mortem: pk_mul cut VALU issue exactly as designed
// (VALUBusy*dur = 0.73x of R13, matching the 0.75 instr ratio), but dur
// REGRESSED 103->131 us because the k-pair-interleaved reads put the 8
// lane-group addresses at 64B stride (ty*16 floats = {0,16} mod 32 banks)
// -> every ds_read_b128 was a 4-way conflict (1.58x, m136) and the DS pipe
// became the critical path (conflicts 3.0M->5.1M, VALUBusy 68%).
// Fix: stride-20 bump. Lane-group g owns 16 contiguous floats at float
// offset 20*g (4-float gap per 8-m group). 20*g mod 32 =
// {0,20,8,28,16,4,24,12}: the 8 simultaneous 16B reads cover all 32 banks
// exactly once -> zero read conflicts. 80B offsets keep b128 alignment.
// Writes (16 of 80 DS ops/stage) stay 4-way as in R13. Row stride 156
// floats; strip = 8*156 = 1248 floats; total LDS 39936B (2 blocks/CU ok).

#define TS 64
#define BK 16
#define RSF 156              // bumped row stride: 7*20 + 16 = 156 floats
#define STRIPF (8 * RSF)     // (BK/2) rows per strip = 1248 floats

typedef __attribute__((ext_vector_type(2))) float f32x2;
typedef __attribute__((ext_vector_type(4))) float f32x4;

__device__ __forceinline__ f32x2 lo2(f32x4 v) { return __builtin_shufflevector(v, v, 0, 1); }
__device__ __forceinline__ f32x2 hi2(f32x4 v) { return __builtin_shufflevector(v, v, 2, 3); }

__device__ __forceinline__ void mam_upd_pk(float& mx, float& mn, f32x2 a, f32x2 b) {
    f32x2 p;
    asm("v_pk_mul_f32 %0, %1, %2" : "=v"(p) : "v"(a), "v"(b));
    asm("v_max3_f32 %0, %1, %2, %0" : "+v"(mx) : "v"(p.x), "v"(p.y));
    asm("v_min3_f32 %0, %1, %2, %0" : "+v"(mn) : "v"(p.x), "v"(p.y));
}

__global__
__attribute__((amdgpu_flat_work_group_size(256, 256)))
__attribute__((amdgpu_waves_per_eu(2, 2)))
void mam_sk(
    const float* __restrict__ A, const float* __restrict__ W,
    const float* __restrict__ bias, float* __restrict__ C,
    int M, int N, int K)
{
    // union: [0..4*STRIPF) sA strips, [4*STRIPF..8*STRIPF) sW strips;
    // after the main loop (barrier) the same memory holds cmx/cmn (64x64 each;
    // 8192 floats <= 8*STRIPF = 9984).
    __shared__ __align__(16) float smem[8 * STRIPF];   // 39936 B
    float* cmx = smem;
    float* cmn = smem + TS * TS;

    const int t    = threadIdx.x;
    const int w    = t >> 6;        // wave id == k-group
    const int lane = t & 63;
    const int ty   = lane >> 3;     // m micro thread (8 rows)
    const int tx   = lane & 7;      // n micro thread (8 cols)
    const int m0   = blockIdx.y * TS;
    const int n0   = blockIdx.x * TS;
    const int kc   = K >> 2;        // 256 k per wave
    const int kb0  = w * kc;

    const int sr = lane >> 2;       // staging row 0..15
    const int sc = lane & 3;        // staging k-quad 0..3

    float* sAw = smem + (size_t)w * STRIPF;          // this wave's A strip
    float* sWw = smem + (size_t)(4 + w) * STRIPF;    // this wave's W strip

    const float* Ap = A + (size_t)(m0 + sr) * K + kb0 + sc * 4;
    const float* Wp = W + (size_t)(n0 + sr) * K + kb0 + sc * 4;

    float mx[8][8], mn[8][8];
#pragma unroll
    for (int i = 0; i < 8; ++i)
#pragma unroll
        for (int j = 0; j < 8; ++j) {
            mx[i][j] = -INFINITY;
            mn[i][j] =  INFINITY;
        }

    float4 ra[4], rw[4];
#pragma unroll
    for (int q = 0; q < 4; ++q) {
        ra[q] = *(const float4*)(Ap + (size_t)q * 16 * K);
        rw[q] = *(const float4*)(Wp + (size_t)q * 16 * K);
    }
    Ap += BK;
    Wp += BK;

    // bumped pair offset for this lane's staging rows (q adds 40 floats):
    // m = sr + 16q -> pair offset 20*((sr>>3) + 2q) + 2*(sr&7)
    const int mo = 20 * (sr >> 3) + 2 * (sr & 7);

    const int nStages = kc / BK;    // 16
    for (int s = 0; s < nStages; ++s) {
        // scatter current stage into this wave's strip, k-pair interleaved
        // with the stride-20 bump; float4 (k0..k3) for row m -> (x,y) to
        // kp-row sc*2, (z,w) to kp-row sc*2+1.
        // (no barrier: strip is wave-private; same-wave DS ops are ordered)
#pragma unroll
        for (int q = 0; q < 4; ++q) {
            const int po = mo + 40 * q;
            *(float2*)&sAw[(sc * 2 + 0) * RSF + po] = make_float2(ra[q].x, ra[q].y);
            *(float2*)&sAw[(sc * 2 + 1) * RSF + po] = make_float2(ra[q].z, ra[q].w);
            *(float2*)&sWw[(sc * 2 + 0) * RSF + po] = make_float2(rw[q].x, rw[q].y);
            *(float2*)&sWw[(sc * 2 + 1) * RSF + po] = make_float2(rw[q].z, rw[q].w);
        }
        // prefetch next stage while computing this one
        if (s + 1 < nStages) {
#pragma unroll
            for (int q = 0; q < 4; ++q) {
                ra[q] = *(const float4*)(Ap + (size_t)q * 16 * K);
                rw[q] = *(const float4*)(Wp + (size_t)q * 16 * K);
            }
            Ap += BK;
            Wp += BK;
        }

#pragma unroll
        for (int kp = 0; kp < BK / 2; ++kp) {
            const float* rA = sAw + kp * RSF + ty * 20;
            const float* rW = sWw + kp * RSF + tx * 20;
            f32x4 A0 = *(const f32x4*)(rA + 0);
            f32x4 A1 = *(const f32x4*)(rA + 4);
            f32x4 A2 = *(const f32x4*)(rA + 8);
            f32x4 A3 = *(const f32x4*)(rA + 12);
            f32x4 W0 = *(const f32x4*)(rW + 0);
            f32x4 W1 = *(const f32x4*)(rW + 4);
            f32x4 W2 = *(const f32x4*)(rW + 8);
            f32x4 W3 = *(const f32x4*)(rW + 12);

            f32x2 av[8] = {lo2(A0), hi2(A0), lo2(A1), hi2(A1),
                           lo2(A2), hi2(A2), lo2(A3), hi2(A3)};
            f32x2 bv[8] = {lo2(W0), hi2(W0), lo2(W1), hi2(W1),
                           lo2(W2), hi2(W2), lo2(W3), hi2(W3)};

#pragma unroll
            for (int i = 0; i < 8; ++i)
#pragma unroll
                for (int j = 0; j < 8; ++j)
                    mam_upd_pk(mx[i][j], mn[i][j], av[i], bv[j]);
        }
    }

    // strips now dead; cmx/cmn overlap them -> drain all waves first
    __syncthreads();

    // ---- cross-wave combine: sequential merge rounds through LDS ----
    for (int rnd = 0; rnd < 4; ++rnd) {
        if (w == rnd) {
#pragma unroll
            for (int i = 0; i < 8; ++i)
#pragma unroll
                for (int j = 0; j < 8; ++j) {
                    const int idx = (ty * 8 + i) * TS + tx * 8 + j;
                    if (rnd == 0) {
                        cmx[idx] = mx[i][j];
                        cmn[idx] = mn[i][j];
                    } else {
                        cmx[idx] = fmaxf(cmx[idx], mx[i][j]);
                        cmn[idx] = fminf(cmn[idx], mn[i][j]);
                    }
                }
        }
        __syncthreads();
    }

    // ---- bias + store: wave w writes micro-rows i = {2w, 2w+1} ----
    float4 blo = *(const float4*)(bias + n0 + tx * 8);
    float4 bhi = *(const float4*)(bias + n0 + tx * 8 + 4);
#pragma unroll
    for (int i2 = 0; i2 < 2; ++i2) {
        const int i   = w * 2 + i2;
        const int row = ty * 8 + i;
        const int idx = row * TS + tx * 8;
        float4 o0, o1;
        o0.x = cmx[idx + 0] + cmn[idx + 0] + blo.x;
        o0.y = cmx[idx + 1] + cmn[idx + 1] + blo.y;
        o0.z = cmx[idx + 2] + cmn[idx + 2] + blo.z;
        o0.w = cmx[idx + 3] + cmn[idx + 3] + blo.w;
        o1.x = cmx[idx + 4] + cmn[idx + 4] + bhi.x;
        o1.y = cmx[idx + 5] + cmn[idx + 5] + bhi.y;
        o1.z = cmx[idx + 6] + cmn[idx + 6] + bhi.z;
        o1.w = cmx[idx + 7] + cmn[idx + 7] + bhi.w;
        float4* p = (float4*)(C + (size_t)(m0 + row) * N + n0 + tx * 8);
        p[0] = o0;
        p[1] = o1;
    }
}

// ---- fallback (proven R2 kernel) for shapes the fast path can't take ----
#define BM 64
#define BN 64
#define FBK 32
#define LDSW 68

__device__ __forceinline__ void mam_upd_fb(float& mx, float& mn, float p0, float p1) {
    float nmx, nmn;
    asm("v_max3_f32 %0, %1, %2, %3" : "=v"(nmx) : "v"(p0), "v"(p1), "v"(mx));
    asm("v_min3_f32 %0, %1, %2, %3" : "=v"(nmn) : "v"(p0), "v"(p1), "v"(mn));
    mx = nmx;
    mn = nmn;
}

__global__ __launch_bounds__(256) void mam_fallback(
    const float* __restrict__ A, const float* __restrict__ W,
    const float* __restrict__ bias, float* __restrict__ C,
    int M, int N, int K)
{
    __shared__ float Asf[FBK][LDSW];
    __shared__ float Wsf[FBK][LDSW];

    const int t  = threadIdx.x;
    const int tx = t & 15;
    const int ty = t >> 4;
    const int m0 = blockIdx.y * BM;
    const int n0 = blockIdx.x * BN;
    const int r  = t >> 3;
    const int kq = t & 7;

    const float* Aptr = A + (size_t)(m0 + r) * K + kq * 4;
    const float* Wptr = W + (size_t)(n0 + r) * K + kq * 4;

    float vmax[4][4], vmin[4][4];
#pragma unroll
    for (int i = 0; i < 4; ++i)
#pragma unroll
        for (int j = 0; j < 4; ++j) {
            vmax[i][j] = -INFINITY;
            vmin[i][j] =  INFINITY;
        }

    for (int k0 = 0; k0 < K; k0 += FBK) {
        float4 a0 = *(const float4*)(Aptr);
        float4 a1 = *(const float4*)(Aptr + (size_t)32 * K);
        float4 w0 = *(const float4*)(Wptr);
        float4 w1 = *(const float4*)(Wptr + (size_t)32 * K);
        Aptr += FBK;
        Wptr += FBK;

        const int kk = kq * 4;
        Asf[kk + 0][r]      = a0.x;
        Asf[kk + 1][r]      = a0.y;
        Asf[kk + 2][r]      = a0.z;
        Asf[kk + 3][r]      = a0.w;
        Asf[kk + 0][r + 32] = a1.x;
        Asf[kk + 1][r + 32] = a1.y;
        Asf[kk + 2][r + 32] = a1.z;
        Asf[kk + 3][r + 32] = a1.w;

        Wsf[kk + 0][r]      = w0.x;
        Wsf[kk + 1][r]      = w0.y;
        Wsf[kk + 2][r]      = w0.z;
        Wsf[kk + 3][r]      = w0.w;
        Wsf[kk + 0][r + 32] = w1.x;
        Wsf[kk + 1][r + 32] = w1.y;
        Wsf[kk + 2][r + 32] = w1.z;
        Wsf[kk + 3][r + 32] = w1.w;

        __syncthreads();

#pragma unroll
        for (int k = 0; k < FBK; k += 2) {
            float4 ta0 = *(const float4*)&Asf[k    ][ty * 4];
            float4 ta1 = *(const float4*)&Asf[k + 1][ty * 4];
            float4 tb0 = *(const float4*)&Wsf[k    ][tx * 4];
            float4 tb1 = *(const float4*)&Wsf[k + 1][tx * 4];

            float a0v[4] = {ta0.x, ta0.y, ta0.z, ta0.w};
            float a1v[4] = {ta1.x, ta1.y, ta1.z, ta1.w};
            float b0v[4] = {tb0.x, tb0.y, tb0.z, tb0.w};
            float b1v[4] = {tb1.x, tb1.y, tb1.z, tb1.w};

#pragma unroll
            for (int i = 0; i < 4; ++i)
#pragma unroll
                for (int j = 0; j < 4; ++j) {
                    float p0 = a0v[i] * b0v[j];
                    float p1 = a1v[i] * b1v[j];
                    mam_upd_fb(vmax[i][j], vmin[i][j], p0, p1);
                }
        }
        __syncthreads();
    }

    float4 bv = *(const float4*)(bias + n0 + tx * 4);
#pragma unroll
    for (int i = 0; i < 4; ++i) {
        float4 o;
        o.x = vmax[i][0] + vmin[i][0] + bv.x;
        o.y = vmax[i][1] + vmin[i][1] + bv.y;
        o.z = vmax[i][2] + vmin[i][2] + bv.z;
        o.w = vmax[i][3] + vmin[i][3] + bv.w;
        *(float4*)(C + (size_t)(m0 + ty * 4 + i) * N + n0 + tx * 4) = o;
    }
}

extern "C" void kernel_launch(void* const* d_in, const int* in_sizes, int n_in,
                              void* d_out, int out_size, void* d_ws, size_t ws_size,
                              hipStream_t stream) {
    const float* x    = (const float*)d_in[0];
    const float* w    = (const float*)d_in[1];
    const float* bias = (const float*)d_in[2];
    float* out = (float*)d_out;

    const int N = in_sizes[2];
    const int K = in_sizes[1] / N;
    const int M = in_sizes[0] / K;

    const bool fast_ok = (K % (4 * BK) == 0) && (M % TS == 0) && (N % TS == 0);

    if (fast_ok) {
        dim3 grid(N / TS, M / TS);   // (16, 32) = 512 blocks
        mam_sk<<<grid, 256, 0, stream>>>(x, w, bias, out, M, N, K);
    } else {
        dim3 grid(N / BN, M / BM);
        mam_fallback<<<grid, 256, 0, stream>>>(x, w, bias, out, M, N, K);
    }
}